// Round 14
// baseline (322.955 us; speedup 1.0000x reference)
//
#include <hip/hip_runtime.h>
#include <hip/hip_fp16.h>
#include <math.h>

#define NN 50000
#define NE 1600000
#define NBIN 512       // fine dst bins; one k_edge3 block owns one bin
#define DSTF 98        // dsts per bin; 512*98 = 50176 >= NN
#define NREP 8         // bucket replicas (XCD-local append regions)
#define PCAP 24        // per-(block,bin) LDS stage cap (mean 4, +10 sigma)
#define BCAPR 576      // per-(rep,bin) bucket cap (mean 391, +9 sigma)

__device__ __forceinline__ float wave_sum(float v) {
    #pragma unroll
    for (int off = 32; off > 0; off >>= 1) v += __shfl_xor(v, off, 64);
    return v;
}

// ---------------- K0a: GAT-side node precompute ----------------
// W in LDS; x tile staged coalesced into LDS; compute reads LDS only.
// t-loop MUST stay rolled (#pragma unroll 1): full unroll exposes 288
// ds_read_b128 whose results LLVM hoists -> >256 VGPR -> scratch spill
// (R8: 849us, R9: 557us, both with GB-scale FETCH/WRITE from spill).
// Output goes into the INTERLEAVED xch buffer (L halves 0..63 of each
// 128-half node row; GCN fills 64..127) so k_gather3 reads one row/edge.
__global__ __launch_bounds__(256) void k_node_gat(
    const float* __restrict__ x_local, const float* __restrict__ gat_w,
    const float* __restrict__ att_src, const float* __restrict__ att_dst,
    const float* __restrict__ nf, const float* __restrict__ coord,
    const float* __restrict__ fc1_w, const float* __restrict__ fc1_b,
    const float* __restrict__ fc2_w, const float* __restrict__ fc2_b,
    __half* __restrict__ xch,
    float4* __restrict__ snode, float4* __restrict__ dnode,
    float* __restrict__ ps)
{
    __shared__ float wL[64 * 132];              // 33.8 KB W, [h][k] stride 132
    __shared__ float xt[32 * 128];              // 16 KB x tile (32 nodes)
    for (int f = threadIdx.x; f < 64 * 128; f += 256) {
        int h = f >> 7, k = f & 127;
        wL[h * 132 + k] = gat_w[f];
    }
    const int lane = threadIdx.x & 63;
    const int wid  = threadIdx.x >> 6;
    const float asv = att_src[lane];
    const float adv = att_dst[lane];
    const float4* wrow = (const float4*)(wL + lane * 132);
    float4* xts = (float4*)xt;
    const float4* xp = (const float4*)x_local;
    for (int base = blockIdx.x * 32; base < NN; base += gridDim.x * 32) {
        __syncthreads();                        // W staged / prev tile done
        #pragma unroll
        for (int k = 0; k < 4; k++) {
            int gi = base * 32 + (int)threadIdx.x + k * 256;
            if (gi < NN * 32) xts[threadIdx.x + k * 256] = xp[gi];
        }
        __syncthreads();
        float acc[8] = {0.f,0.f,0.f,0.f,0.f,0.f,0.f,0.f};
        const float4* xrow = (const float4*)(xt + wid * 8 * 128);
        #pragma unroll 1
        for (int t = 0; t < 32; t++) {
            float4 wv = wrow[t];                // per-lane ds_read_b128
            #pragma unroll
            for (int j = 0; j < 8; j++) {
                float4 xv = xrow[j * 32 + t];   // wave-uniform LDS broadcast
                acc[j] = fmaf(xv.x, wv.x, acc[j]);
                acc[j] = fmaf(xv.y, wv.y, acc[j]);
                acc[j] = fmaf(xv.z, wv.z, acc[j]);
                acc[j] = fmaf(xv.w, wv.w, acc[j]);
            }
        }
        float sv[8], dv[8];
        #pragma unroll
        for (int j = 0; j < 8; j++) {
            int n = base + wid * 8 + j;
            if (n < NN) xch[(size_t)n * 128 + lane] = __float2half(acc[j]);
            sv[j] = wave_sum(acc[j] * asv);
            dv[j] = wave_sum(acc[j] * adv);
        }
        if (lane < 8) {
            int n = base + wid * 8 + lane;
            if (n < NN) {
                float svx = (lane==0)?sv[0]:(lane==1)?sv[1]:(lane==2)?sv[2]:(lane==3)?sv[3]
                           :(lane==4)?sv[4]:(lane==5)?sv[5]:(lane==6)?sv[6]:sv[7];
                float dvx = (lane==0)?dv[0]:(lane==1)?dv[1]:(lane==2)?dv[2]:(lane==3)?dv[3]
                           :(lane==4)?dv[4]:(lane==5)?dv[5]:(lane==6)?dv[6]:dv[7];
                float xvv[10];
                #pragma unroll
                for (int k = 0; k < 10; k++) xvv[k] = nf[n * 10 + k];
                float niv = fc2_b[0];
                #pragma unroll
                for (int j = 0; j < 10; j++) {
                    float h = fc1_b[j];
                    #pragma unroll
                    for (int k = 0; k < 10; k++) h = fmaf(xvv[k], fc1_w[j * 10 + k], h);
                    h = (h > 0.f) ? h : expm1f(h);
                    niv = fmaf(h, fc2_w[j], niv);
                }
                float cx = coord[2 * n], cy = coord[2 * n + 1];
                float es = svx + dvx;
                es = (es >= 0.f) ? es : 0.2f * es;
                snode[n] = make_float4(cx, cy, svx, niv);
                dnode[n] = make_float4(cx, cy, dvx, 0.f);
                ps[n] = __expf(es);
            }
        }
    }
}

// ---------------- K0b: GCN-side node precompute ----------------
__global__ __launch_bounds__(256) void k_node_gcn(
    const float* __restrict__ x_global, const float* __restrict__ gcn_w,
    __half* __restrict__ xch)
{
    __shared__ float wL[64 * 132];
    __shared__ float xt[32 * 128];
    for (int f = threadIdx.x; f < 64 * 128; f += 256) {
        int h = f >> 7, k = f & 127;
        wL[h * 132 + k] = gcn_w[f];
    }
    const int lane = threadIdx.x & 63;
    const int wid  = threadIdx.x >> 6;
    const float4* wrow = (const float4*)(wL + lane * 132);
    float4* xts = (float4*)xt;
    const float4* xp = (const float4*)x_global;
    for (int base = blockIdx.x * 32; base < NN; base += gridDim.x * 32) {
        __syncthreads();
        #pragma unroll
        for (int k = 0; k < 4; k++) {
            int gi = base * 32 + (int)threadIdx.x + k * 256;
            if (gi < NN * 32) xts[threadIdx.x + k * 256] = xp[gi];
        }
        __syncthreads();
        float acc[8] = {0.f,0.f,0.f,0.f,0.f,0.f,0.f,0.f};
        const float4* xrow = (const float4*)(xt + wid * 8 * 128);
        #pragma unroll 1
        for (int t = 0; t < 32; t++) {
            float4 wv = wrow[t];
            #pragma unroll
            for (int j = 0; j < 8; j++) {
                float4 xv = xrow[j * 32 + t];
                acc[j] = fmaf(xv.x, wv.x, acc[j]);
                acc[j] = fmaf(xv.y, wv.y, acc[j]);
                acc[j] = fmaf(xv.z, wv.z, acc[j]);
                acc[j] = fmaf(xv.w, wv.w, acc[j]);
            }
        }
        #pragma unroll
        for (int j = 0; j < 8; j++) {
            int n = base + wid * 8 + j;
            if (n < NN) xch[(size_t)n * 128 + 64 + lane] = __float2half(acc[j]);
        }
    }
}

// ---------------- P0: zero bucket counters ----------------
__global__ __launch_bounds__(256) void k_zerog(unsigned int* __restrict__ gcnt)
{
    int i = blockIdx.x * 256 + threadIdx.x;
    if (i < NREP * NBIN) gcnt[i] = 0u;
}

// ---------------- P1: LDS-staged radix partition into 512 fine bins ------
__global__ __launch_bounds__(256) void k_part2(
    const int* __restrict__ ei,
    unsigned int* __restrict__ bucket, unsigned int* __restrict__ gcnt)
{
    __shared__ unsigned int lcnt[NBIN];
    __shared__ unsigned int lbase[NBIN];
    __shared__ unsigned int lbuf[NBIN][PCAP];   // 512*24*4 = 48 KiB
    const int rep = blockIdx.x & 7;
    for (int t = threadIdx.x; t < NBIN; t += 256) lcnt[t] = 0u;
    __syncthreads();
    const int base = blockIdx.x * 2048;
    #pragma unroll
    for (int k = 0; k < 8; k++) {
        int i = base + k * 256 + threadIdx.x;
        if (i < NE) {
            int d = ei[NE + i];
            int s = ei[i];
            int b = d / DSTF;
            unsigned int pk = (unsigned int)s | ((unsigned int)(d - b * DSTF) << 16);
            unsigned int slot = atomicAdd(&lcnt[b], 1u);
            if (slot < PCAP) {
                lbuf[b][slot] = pk;
            } else {                            // ~never (+10 sigma); insurance
                unsigned int g = atomicAdd(&gcnt[rep * NBIN + b], 1u);
                if (g < BCAPR) bucket[(size_t)(rep * NBIN + b) * BCAPR + g] = pk;
            }
        }
    }
    __syncthreads();
    for (int t = threadIdx.x; t < NBIN; t += 256) {
        unsigned int n = lcnt[t];
        if (n > PCAP) n = PCAP;
        lcnt[t] = n;
        lbase[t] = n ? atomicAdd(&gcnt[rep * NBIN + t], n) : 0u;
    }
    __syncthreads();
    for (int t = threadIdx.x; t < NBIN; t += 256) {
        unsigned int n = lcnt[t];
        unsigned int gb = lbase[t];
        unsigned int* dst = bucket + (size_t)(rep * NBIN + t) * BCAPR;
        for (unsigned int e = 0; e < n; e++) {
            unsigned int g = gb + e;
            if (g < BCAPR) dst[g] = lbuf[t][e];
        }
    }
}

// ---------------- K1: per-bin edge pass, ZERO global atomics -------------
__global__ __launch_bounds__(512) void k_edge3(
    const unsigned int* __restrict__ bucket, const unsigned int* __restrict__ gcnt,
    const float4* __restrict__ snode, const float4* __restrict__ dnode,
    uint2* __restrict__ rec, unsigned int* __restrict__ offA,
    unsigned int* __restrict__ cntA, float* __restrict__ dis)
{
    const int bin = blockIdx.x;
    const int d0  = bin * DSTF;
    __shared__ unsigned int cnt[DSTF], off[DSTF], cur[DSTF], ews[DSTF];
    __shared__ float4 dnd[DSTF];
    __shared__ unsigned int segc[NREP];
    __shared__ unsigned int sm[128];
    __shared__ unsigned int wsum[8];
    __shared__ unsigned int sbase;
    for (int t = threadIdx.x; t < DSTF; t += 512) {
        cnt[t] = 0u; cur[t] = 0u; ews[t] = 0u;
        int d = d0 + t;
        dnd[t] = (d < NN) ? dnode[d] : make_float4(0.f, 0.f, 0.f, 0.f);
    }
    if (threadIdx.x < NREP) {
        unsigned int c = gcnt[threadIdx.x * NBIN + bin];
        segc[threadIdx.x] = (c > BCAPR) ? BCAPR : c;
    }
    unsigned int partial = 0u;
    for (int idx = threadIdx.x; idx < NREP * NBIN; idx += 512) {
        int b = idx & (NBIN - 1);
        if (b < bin) {
            unsigned int c = gcnt[(idx >> 9) * NBIN + b];
            partial += (c > BCAPR) ? BCAPR : c;
        }
    }
    #pragma unroll
    for (int o = 32; o > 0; o >>= 1) partial += __shfl_xor(partial, o, 64);
    if ((threadIdx.x & 63) == 0) wsum[threadIdx.x >> 6] = partial;
    __syncthreads();
    if (threadIdx.x == 0) {
        unsigned int a = 0;
        #pragma unroll
        for (int r = 0; r < 8; r++) a += wsum[r];
        sbase = a;
    }
    __syncthreads();
    #pragma unroll
    for (int r = 0; r < NREP; r++) {
        unsigned int c = segc[r];
        const unsigned int* bk = bucket + (size_t)(r * NBIN + bin) * BCAPR;
        for (unsigned int t = threadIdx.x; t < c; t += 512)
            atomicAdd(&cnt[bk[t] >> 16], 1u);
    }
    __syncthreads();
    if (threadIdx.x < 128) sm[threadIdx.x] = (threadIdx.x < DSTF) ? cnt[threadIdx.x] : 0u;
    __syncthreads();
    for (int o = 1; o < 128; o <<= 1) {
        unsigned int t = 0;
        if (threadIdx.x < 128 && threadIdx.x >= o) t = sm[threadIdx.x - o];
        __syncthreads();
        if (threadIdx.x < 128) sm[threadIdx.x] += t;
        __syncthreads();
    }
    if (threadIdx.x < DSTF) off[threadIdx.x] = sbase + sm[threadIdx.x] - cnt[threadIdx.x];
    __syncthreads();
    #pragma unroll
    for (int r = 0; r < NREP; r++) {
        unsigned int c = segc[r];
        const unsigned int* bk = bucket + (size_t)(r * NBIN + bin) * BCAPR;
        for (unsigned int t = threadIdx.x; t < c; t += 512) {
            unsigned int pk = bk[t];
            int dl = (int)(pk >> 16);
            int s  = (int)(pk & 0xFFFFu);
            float4 sv = snode[s];
            float4 dv = dnd[dl];
            float dx = sv.x - dv.x, dy = sv.y - dv.y;
            float gw = __expf((dx * dx + dy * dy) * (-1.0f / 1800.0f));
            float tt = fmaf(gw, 1.0f + sv.w, -1.0f);
            float sg = 1.0f / (1.0f + __expf(-tt));
            float w  = fmaf(1.9f, sg, 0.1f);
            float e  = sv.z + dv.z;
            e = (e >= 0.f) ? e : 0.2f * e;
            float ewv = (w >= 0.2f) ? w : 0.0f;
            float p = (ewv != 0.f) ? __expf(e) : 0.0f;
            unsigned int rk = atomicAdd(&cur[dl], 1u);
            atomicAdd(&ews[dl], (unsigned int)(ewv * 16777216.0f + 0.5f));
            __half2 h = __floats2half2_rn(p, ewv);
            rec[off[dl] + rk] = make_uint2((unsigned int)s, *(unsigned int*)&h);
        }
    }
    __syncthreads();
    for (int t = threadIdx.x; t < DSTF; t += 512) {
        int d = d0 + t;
        if (d < NN) {
            offA[d] = off[t];
            cntA[d] = cnt[t];
            dis[d]  = rsqrtf(1.0f + (float)ews[t] * (1.0f / 16777216.0f));
        }
    }
}

// ---------------- K3: fused gather, 8 groups x 8 lanes x uint4 ----------
// R13's 4x16xuint2 issued 1 row-load instr per 8B of feature data (66us,
// HBM 2.7 TB/s, neither pipe saturated -> load-issue bound). Interleaved
// xch rows (256B: L then C) + uint4 (16B) lane reads double edges/instr:
// 8 edge-groups of 8 lanes; per pair-iteration 8 loads serve 16 edges.
__global__ __launch_bounds__(256) void k_gather3(
    const __half* __restrict__ xch,
    const float* __restrict__ ps, const float* __restrict__ dis,
    const unsigned int* __restrict__ offA, const unsigned int* __restrict__ cntA,
    const uint2* __restrict__ rec,
    const float* __restrict__ gat_b, const float* __restrict__ gcn_b,
    uint2* __restrict__ catLh, uint2* __restrict__ catGh)
{
    const int lane = threadIdx.x & 63;
    const int wid  = threadIdx.x >> 6;
    const int eg   = lane >> 3;          // 0..7 edge group
    const int q    = lane & 7;           // uint4 slot within row half
    const int fi   = q * 8;              // first half-index of this lane
    const float g0 = (eg == 0) ? 1.0f : 0.0f;
    const float4 gb0 = *(const float4*)(gat_b + fi);
    const float4 gb1 = *(const float4*)(gat_b + fi + 4);
    const float4 cb0 = *(const float4*)(gcn_b + fi);
    const float4 cb1 = *(const float4*)(gcn_b + fi + 4);
    for (int n = blockIdx.x * 4 + wid; n < NN; n += gridDim.x * 4) {
        float psv = ps[n] * g0;
        float dd = dis[n];
        int beg = (int)offA[n];
        int end = beg + (int)cntA[n];
        const uint4* rowd = (const uint4*)(xch + (size_t)n * 128);
        uint4 us = rowd[q];
        uint4 ug = rowd[q + 8];
        float2 d0 = __half22float2(*(const __half2*)&us.x);
        float2 d1 = __half22float2(*(const __half2*)&us.y);
        float2 d2 = __half22float2(*(const __half2*)&us.z);
        float2 d3 = __half22float2(*(const __half2*)&us.w);
        float2 e0 = __half22float2(*(const __half2*)&ug.x);
        float2 e1 = __half22float2(*(const __half2*)&ug.y);
        float2 e2 = __half22float2(*(const __half2*)&ug.z);
        float2 e3 = __half22float2(*(const __half2*)&ug.w);
        float aL[8], aC[8];
        aL[0] = psv * d0.x; aL[1] = psv * d0.y; aL[2] = psv * d1.x; aL[3] = psv * d1.y;
        aL[4] = psv * d2.x; aL[5] = psv * d2.y; aL[6] = psv * d3.x; aL[7] = psv * d3.y;
        float sw = dd * g0;
        aC[0] = sw * e0.x; aC[1] = sw * e0.y; aC[2] = sw * e1.x; aC[3] = sw * e1.y;
        aC[4] = sw * e2.x; aC[5] = sw * e2.y; aC[6] = sw * e3.x; aC[7] = sw * e3.y;
        float den = psv;
        int j = beg + eg;
        for (; j + 8 < end; j += 16) {
            uint2 r0 = rec[j];
            uint2 r1 = rec[j + 8];
            int s0 = (int)r0.x;
            int s1 = (int)r1.x;
            float2 pc0 = __half22float2(*(const __half2*)&r0.y);
            float2 pc1 = __half22float2(*(const __half2*)&r1.y);
            float c0 = dis[s0] * pc0.y;
            float c1 = dis[s1] * pc1.y;
            const uint4* row0 = (const uint4*)(xch + (size_t)s0 * 128);
            const uint4* row1 = (const uint4*)(xch + (size_t)s1 * 128);
            uint4 l0 = row0[q];
            uint4 g0v = row0[q + 8];
            uint4 l1 = row1[q];
            uint4 g1v = row1[q + 8];
            float2 t0, t1, t2, t3;
            t0 = __half22float2(*(const __half2*)&l0.x);
            t1 = __half22float2(*(const __half2*)&l0.y);
            t2 = __half22float2(*(const __half2*)&l0.z);
            t3 = __half22float2(*(const __half2*)&l0.w);
            aL[0] = fmaf(pc0.x, t0.x, aL[0]); aL[1] = fmaf(pc0.x, t0.y, aL[1]);
            aL[2] = fmaf(pc0.x, t1.x, aL[2]); aL[3] = fmaf(pc0.x, t1.y, aL[3]);
            aL[4] = fmaf(pc0.x, t2.x, aL[4]); aL[5] = fmaf(pc0.x, t2.y, aL[5]);
            aL[6] = fmaf(pc0.x, t3.x, aL[6]); aL[7] = fmaf(pc0.x, t3.y, aL[7]);
            t0 = __half22float2(*(const __half2*)&g0v.x);
            t1 = __half22float2(*(const __half2*)&g0v.y);
            t2 = __half22float2(*(const __half2*)&g0v.z);
            t3 = __half22float2(*(const __half2*)&g0v.w);
            aC[0] = fmaf(c0, t0.x, aC[0]); aC[1] = fmaf(c0, t0.y, aC[1]);
            aC[2] = fmaf(c0, t1.x, aC[2]); aC[3] = fmaf(c0, t1.y, aC[3]);
            aC[4] = fmaf(c0, t2.x, aC[4]); aC[5] = fmaf(c0, t2.y, aC[5]);
            aC[6] = fmaf(c0, t3.x, aC[6]); aC[7] = fmaf(c0, t3.y, aC[7]);
            t0 = __half22float2(*(const __half2*)&l1.x);
            t1 = __half22float2(*(const __half2*)&l1.y);
            t2 = __half22float2(*(const __half2*)&l1.z);
            t3 = __half22float2(*(const __half2*)&l1.w);
            aL[0] = fmaf(pc1.x, t0.x, aL[0]); aL[1] = fmaf(pc1.x, t0.y, aL[1]);
            aL[2] = fmaf(pc1.x, t1.x, aL[2]); aL[3] = fmaf(pc1.x, t1.y, aL[3]);
            aL[4] = fmaf(pc1.x, t2.x, aL[4]); aL[5] = fmaf(pc1.x, t2.y, aL[5]);
            aL[6] = fmaf(pc1.x, t3.x, aL[6]); aL[7] = fmaf(pc1.x, t3.y, aL[7]);
            t0 = __half22float2(*(const __half2*)&g1v.x);
            t1 = __half22float2(*(const __half2*)&g1v.y);
            t2 = __half22float2(*(const __half2*)&g1v.z);
            t3 = __half22float2(*(const __half2*)&g1v.w);
            aC[0] = fmaf(c1, t0.x, aC[0]); aC[1] = fmaf(c1, t0.y, aC[1]);
            aC[2] = fmaf(c1, t1.x, aC[2]); aC[3] = fmaf(c1, t1.y, aC[3]);
            aC[4] = fmaf(c1, t2.x, aC[4]); aC[5] = fmaf(c1, t2.y, aC[5]);
            aC[6] = fmaf(c1, t3.x, aC[6]); aC[7] = fmaf(c1, t3.y, aC[7]);
            den += pc0.x + pc1.x;
        }
        if (j < end) {
            uint2 r0 = rec[j];
            int s0 = (int)r0.x;
            float2 pc0 = __half22float2(*(const __half2*)&r0.y);
            float c0 = dis[s0] * pc0.y;
            const uint4* row0 = (const uint4*)(xch + (size_t)s0 * 128);
            uint4 l0 = row0[q];
            uint4 g0v = row0[q + 8];
            float2 t0, t1, t2, t3;
            t0 = __half22float2(*(const __half2*)&l0.x);
            t1 = __half22float2(*(const __half2*)&l0.y);
            t2 = __half22float2(*(const __half2*)&l0.z);
            t3 = __half22float2(*(const __half2*)&l0.w);
            aL[0] = fmaf(pc0.x, t0.x, aL[0]); aL[1] = fmaf(pc0.x, t0.y, aL[1]);
            aL[2] = fmaf(pc0.x, t1.x, aL[2]); aL[3] = fmaf(pc0.x, t1.y, aL[3]);
            aL[4] = fmaf(pc0.x, t2.x, aL[4]); aL[5] = fmaf(pc0.x, t2.y, aL[5]);
            aL[6] = fmaf(pc0.x, t3.x, aL[6]); aL[7] = fmaf(pc0.x, t3.y, aL[7]);
            t0 = __half22float2(*(const __half2*)&g0v.x);
            t1 = __half22float2(*(const __half2*)&g0v.y);
            t2 = __half22float2(*(const __half2*)&g0v.z);
            t3 = __half22float2(*(const __half2*)&g0v.w);
            aC[0] = fmaf(c0, t0.x, aC[0]); aC[1] = fmaf(c0, t0.y, aC[1]);
            aC[2] = fmaf(c0, t1.x, aC[2]); aC[3] = fmaf(c0, t1.y, aC[3]);
            aC[4] = fmaf(c0, t2.x, aC[4]); aC[5] = fmaf(c0, t2.y, aC[5]);
            aC[6] = fmaf(c0, t3.x, aC[6]); aC[7] = fmaf(c0, t3.y, aC[7]);
            den += pc0.x;
        }
        #pragma unroll
        for (int m = 8; m <= 32; m <<= 1) {
            #pragma unroll
            for (int k = 0; k < 8; k++) {
                aL[k] += __shfl_xor(aL[k], m, 64);
                aC[k] += __shfl_xor(aC[k], m, 64);
            }
            den += __shfl_xor(den, m, 64);
        }
        if (eg == 0) {
            float rd = 1.0f / den;
            float la[8], ga[8];
            la[0] = fmaf(aL[0], rd, gb0.x); la[1] = fmaf(aL[1], rd, gb0.y);
            la[2] = fmaf(aL[2], rd, gb0.z); la[3] = fmaf(aL[3], rd, gb0.w);
            la[4] = fmaf(aL[4], rd, gb1.x); la[5] = fmaf(aL[5], rd, gb1.y);
            la[6] = fmaf(aL[6], rd, gb1.z); la[7] = fmaf(aL[7], rd, gb1.w);
            ga[0] = fmaxf(fmaf(dd, aC[0], cb0.x), 0.f);
            ga[1] = fmaxf(fmaf(dd, aC[1], cb0.y), 0.f);
            ga[2] = fmaxf(fmaf(dd, aC[2], cb0.z), 0.f);
            ga[3] = fmaxf(fmaf(dd, aC[3], cb0.w), 0.f);
            ga[4] = fmaxf(fmaf(dd, aC[4], cb1.x), 0.f);
            ga[5] = fmaxf(fmaf(dd, aC[5], cb1.y), 0.f);
            ga[6] = fmaxf(fmaf(dd, aC[6], cb1.z), 0.f);
            ga[7] = fmaxf(fmaf(dd, aC[7], cb1.w), 0.f);
            #pragma unroll
            for (int k = 0; k < 8; k++)
                la[k] = (la[k] > 0.f) ? la[k] : expm1f(la[k]);
            __half2 l01 = __floats2half2_rn(la[0], la[1]);
            __half2 l23 = __floats2half2_rn(la[2], la[3]);
            __half2 l45 = __floats2half2_rn(la[4], la[5]);
            __half2 l67 = __floats2half2_rn(la[6], la[7]);
            __half2 g01 = __floats2half2_rn(ga[0], ga[1]);
            __half2 g23 = __floats2half2_rn(ga[2], ga[3]);
            __half2 g45 = __floats2half2_rn(ga[4], ga[5]);
            __half2 g67 = __floats2half2_rn(ga[6], ga[7]);
            catLh[(size_t)n * 16 + q * 2] =
                make_uint2(*(unsigned int*)&l01, *(unsigned int*)&l23);
            catLh[(size_t)n * 16 + q * 2 + 1] =
                make_uint2(*(unsigned int*)&l45, *(unsigned int*)&l67);
            catGh[(size_t)n * 16 + q * 2] =
                make_uint2(*(unsigned int*)&g01, *(unsigned int*)&g23);
            catGh[(size_t)n * 16 + q * 2 + 1] =
                make_uint2(*(unsigned int*)&g45, *(unsigned int*)&g67);
        }
    }
}

// ---------------- K4: fusion head, LDS-staged weights ----------------
// w1 staged in LDS once per block; 32 nodes x 8 q-slices. j rotated by q
// (jj=(q+j)&7) so 8 concurrent w rows (stride 132) hit distinct banks.
// cat staged at uint2-stride 33: conflict-free.
__global__ __launch_bounds__(256) void k_fuse(
    const uint2* __restrict__ catLh, const uint2* __restrict__ catGh,
    const float* __restrict__ fus_w1, const float* __restrict__ fus_b1,
    const float* __restrict__ fus_w2, const float* __restrict__ fus_b2,
    float* __restrict__ out)
{
    __shared__ float wS[64 * 132];      // 33.8 KB
    __shared__ uint2 catS[32 * 33];     // 8.4 KB
    const int nb = blockIdx.x * 32;
    for (int f = threadIdx.x; f < 64 * 128; f += 256) {
        int r = f >> 7, c = f & 127;
        wS[r * 132 + c] = fus_w1[f];
    }
    for (int f = threadIdx.x; f < 32 * 32; f += 256) {
        int i = f >> 5, c = f & 31;
        int n = nb + i;
        uint2 v = make_uint2(0u, 0u);
        if (n < NN) v = (c < 16) ? catLh[(size_t)n * 16 + c]
                                 : catGh[(size_t)n * 16 + (c - 16)];
        catS[i * 33 + c] = v;
    }
    __syncthreads();
    const int p = threadIdx.x >> 3;     // local node 0..31
    const int q = threadIdx.x & 7;      // hid slice
    const int n = nb + p;
    float hid[8];
    #pragma unroll
    for (int j = 0; j < 8; j++) {
        int jj = (q + j) & 7;
        hid[j] = fus_b1[q * 8 + jj];
    }
    const uint2* cp = catS + p * 33;
    #pragma unroll 2
    for (int kb = 0; kb < 32; kb++) {   // unified cols: kb*4 covers 0..127
        uint2 u = cp[kb];
        float2 a = __half22float2(*(const __half2*)&u.x);
        float2 b = __half22float2(*(const __half2*)&u.y);
        #pragma unroll
        for (int j = 0; j < 8; j++) {
            int jj = (q + j) & 7;
            float4 wv = *(const float4*)(wS + (size_t)(q * 8 + jj) * 132 + kb * 4);
            hid[j] = fmaf(wv.x, a.x, hid[j]);
            hid[j] = fmaf(wv.y, a.y, hid[j]);
            hid[j] = fmaf(wv.z, b.x, hid[j]);
            hid[j] = fmaf(wv.w, b.y, hid[j]);
        }
    }
    float acc = 0.f;
    #pragma unroll
    for (int j = 0; j < 8; j++) {
        int jj = (q + j) & 7;
        acc = fmaf(fmaxf(hid[j], 0.f), fus_w2[q * 8 + jj], acc);
    }
    acc += __shfl_xor(acc, 1, 64);
    acc += __shfl_xor(acc, 2, 64);
    acc += __shfl_xor(acc, 4, 64);
    if (q == 0 && n < NN) out[n] = acc + fus_b2[0];
}

extern "C" void kernel_launch(void* const* d_in, const int* in_sizes, int n_in,
                              void* d_out, int out_size, void* d_ws, size_t ws_size,
                              hipStream_t stream)
{
    const float* x_local  = (const float*)d_in[0];
    const float* x_global = (const float*)d_in[1];
    const float* nf       = (const float*)d_in[2];
    const float* coord    = (const float*)d_in[3];
    const int*   ei       = (const int*)d_in[4];
    const float* fc1_w    = (const float*)d_in[5];
    const float* fc1_b    = (const float*)d_in[6];
    const float* fc2_w    = (const float*)d_in[7];
    const float* fc2_b    = (const float*)d_in[8];
    const float* gat_w    = (const float*)d_in[9];
    const float* att_src  = (const float*)d_in[10];
    const float* att_dst  = (const float*)d_in[11];
    const float* gat_b    = (const float*)d_in[12];
    const float* gcn_w    = (const float*)d_in[13];
    const float* gcn_b    = (const float*)d_in[14];
    const float* fus_w1   = (const float*)d_in[15];
    const float* fus_b1   = (const float*)d_in[16];
    const float* fus_w2   = (const float*)d_in[17];
    const float* fus_b2   = (const float*)d_in[18];
    float* out = (float*)d_out;

    char* ws = (char*)d_ws;
    uint2*  rec  = (uint2*) (ws);                       // compact CSR 1.6M*8 = 12,800,000
    __half* xch  = (__half*)(ws + 12800000);            // interleaved L|C, 12,800,000
    uint2*  catLh= (uint2*) (ws + 25600000);            //  6,400,000
    uint2*  catGh= (uint2*) (ws + 32000000);            //  6,400,000
    // bucket OVERLAYS cat region: dead before k_gather3 writes cat*
    unsigned int* bucket = (unsigned int*)(ws + 25600000); // 8*512*576*4 = 9,437,184
    float4* snode= (float4*)(ws + 38400000);            //    800,000
    float4* dnode= (float4*)(ws + 39200000);            //    800,000
    unsigned int* offA = (unsigned int*)(ws + 40000000);//    200,000
    unsigned int* cntA = (unsigned int*)(ws + 40200000);//    200,000
    float*  dis  = (float*) (ws + 40400000);            //    200,000
    float*  ps   = (float*) (ws + 40600000);            //    200,000
    unsigned int* gcnt = (unsigned int*)(ws + 40800000);//     16,384 -> end ~40.82 MB
    (void)in_sizes; (void)n_in; (void)out_size; (void)ws_size;

    k_zerog<<<(NREP * NBIN + 255) / 256, 256, 0, stream>>>(gcnt);
    k_part2<<<782, 256, 0, stream>>>(ei, bucket, gcnt);   // 782*2048 >= NE
    k_node_gat<<<782, 256, 0, stream>>>(x_local, gat_w, att_src, att_dst,
                                        nf, coord, fc1_w, fc1_b, fc2_w, fc2_b,
                                        xch, snode, dnode, ps);
    k_node_gcn<<<782, 256, 0, stream>>>(x_global, gcn_w, xch);
    k_edge3<<<NBIN, 512, 0, stream>>>(bucket, gcnt, snode, dnode,
                                      rec, offA, cntA, dis);
    k_gather3<<<3125, 256, 0, stream>>>(xch, ps, dis, offA, cntA, rec,
                                        gat_b, gcn_b, catLh, catGh);
    k_fuse<<<(NN + 31) / 32, 256, 0, stream>>>(catLh, catGh,
                                               fus_w1, fus_b1, fus_w2, fus_b2, out);
}

// Round 15
// 286.062 us; speedup vs baseline: 1.1290x; 1.1290x over previous
//
#include <hip/hip_runtime.h>
#include <hip/hip_fp16.h>
#include <math.h>

#define NN 50000
#define NE 1600000
#define NBIN 512       // fine dst bins; one k_edge3 block owns one bin
#define DSTF 98        // dsts per bin; 512*98 = 50176 >= NN
#define NREP 8         // bucket replicas (XCD-local append regions)
#define PCAP 24        // per-(block,bin) LDS stage cap (mean 4, +10 sigma)
#define BCAPR 576      // per-(rep,bin) bucket cap (mean 391, +9 sigma)
#define NBF 782        // blocks per front role

__device__ __forceinline__ float wave_sum(float v) {
    #pragma unroll
    for (int off = 32; off > 0; off >>= 1) v += __shfl_xor(v, off, 64);
    return v;
}

// ---------------- P0: zero bucket counters ----------------
__global__ __launch_bounds__(256) void k_zerog(unsigned int* __restrict__ gcnt)
{
    int i = blockIdx.x * 256 + threadIdx.x;
    if (i < NREP * NBIN) gcnt[i] = 0u;
}

// ---------------- K_FRONT: role-split merge of 3 independent kernels ----
// Roles: blocks 0..781 = edge partition; 782..1563 = GAT GEMM;
// 1564..2345 = GCN GEMM. The three are mutually independent and each is
// latency-limited at 3 blocks/CU; co-residency hides each other's stalls.
// LDS is a 53.2 KB union (partition: 13312 u32; GEMM: 12544 f32).
// GEMM t-loop stays #pragma unroll 1 (R8/R9: full unroll -> VGPR spill).
__global__ __launch_bounds__(256) void k_front(
    const int* __restrict__ ei,
    unsigned int* __restrict__ bucket, unsigned int* __restrict__ gcnt,
    const float* __restrict__ x_local, const float* __restrict__ gat_w,
    const float* __restrict__ att_src, const float* __restrict__ att_dst,
    const float* __restrict__ nf, const float* __restrict__ coord,
    const float* __restrict__ fc1_w, const float* __restrict__ fc1_b,
    const float* __restrict__ fc2_w, const float* __restrict__ fc2_b,
    const float* __restrict__ x_global, const float* __restrict__ gcn_w,
    __half* __restrict__ xch,
    float4* __restrict__ snode, float4* __restrict__ dnode,
    float* __restrict__ ps)
{
    __shared__ unsigned int smem[13312];        // 53,248 B union
    const int bid = blockIdx.x;
    if (bid < NBF) {
        // ================= partition role =================
        unsigned int* lcnt  = smem;                         // [NBIN]
        unsigned int* lbase = smem + NBIN;                  // [NBIN]
        unsigned int (*lbuf)[PCAP] = (unsigned int(*)[PCAP])(smem + 2 * NBIN);
        const int rep = bid & 7;
        for (int t = threadIdx.x; t < NBIN; t += 256) lcnt[t] = 0u;
        __syncthreads();
        const int base = bid * 2048;
        #pragma unroll
        for (int k = 0; k < 8; k++) {
            int i = base + k * 256 + threadIdx.x;
            if (i < NE) {
                int d = ei[NE + i];
                int s = ei[i];
                int b = d / DSTF;
                unsigned int pk = (unsigned int)s | ((unsigned int)(d - b * DSTF) << 16);
                unsigned int slot = atomicAdd(&lcnt[b], 1u);
                if (slot < PCAP) {
                    lbuf[b][slot] = pk;
                } else {                        // ~never (+10 sigma); insurance
                    unsigned int g = atomicAdd(&gcnt[rep * NBIN + b], 1u);
                    if (g < BCAPR) bucket[(size_t)(rep * NBIN + b) * BCAPR + g] = pk;
                }
            }
        }
        __syncthreads();
        for (int t = threadIdx.x; t < NBIN; t += 256) {
            unsigned int n = lcnt[t];
            if (n > PCAP) n = PCAP;
            lcnt[t] = n;
            lbase[t] = n ? atomicAdd(&gcnt[rep * NBIN + t], n) : 0u;
        }
        __syncthreads();
        for (int t = threadIdx.x; t < NBIN; t += 256) {
            unsigned int n = lcnt[t];
            unsigned int gb = lbase[t];
            unsigned int* dst = bucket + (size_t)(rep * NBIN + t) * BCAPR;
            for (unsigned int e = 0; e < n; e++) {
                unsigned int g = gb + e;
                if (g < BCAPR) dst[g] = lbuf[t][e];
            }
        }
    } else {
        // ================= node GEMM roles =================
        const bool isGat = bid < 2 * NBF;
        const int vb = isGat ? bid - NBF : bid - 2 * NBF;
        const float* xsrc = isGat ? x_local : x_global;
        const float* wsrc = isGat ? gat_w : gcn_w;
        float* wL = (float*)smem;                   // [64*132] stride-132 rows
        float* xt = (float*)smem + 64 * 132;        // [32*128] x tile
        for (int f = threadIdx.x; f < 64 * 128; f += 256) {
            int h = f >> 7, k = f & 127;
            wL[h * 132 + k] = wsrc[f];
        }
        const int lane = threadIdx.x & 63;
        const int wid  = threadIdx.x >> 6;
        const float asv = att_src[lane];
        const float adv = att_dst[lane];
        const int ofs = isGat ? 0 : 64;
        const float4* wrow = (const float4*)(wL + lane * 132);
        float4* xts = (float4*)xt;
        const float4* xp = (const float4*)xsrc;
        for (int base = vb * 32; base < NN; base += NBF * 32) {
            __syncthreads();                        // W staged / prev tile done
            #pragma unroll
            for (int k = 0; k < 4; k++) {
                int gi = base * 32 + (int)threadIdx.x + k * 256;
                if (gi < NN * 32) xts[threadIdx.x + k * 256] = xp[gi];
            }
            __syncthreads();
            float acc[8] = {0.f,0.f,0.f,0.f,0.f,0.f,0.f,0.f};
            const float4* xrow = (const float4*)(xt + wid * 8 * 128);
            #pragma unroll 1
            for (int t = 0; t < 32; t++) {
                float4 wv = wrow[t];                // per-lane ds_read_b128
                #pragma unroll
                for (int j = 0; j < 8; j++) {
                    float4 xv = xrow[j * 32 + t];   // wave-uniform LDS broadcast
                    acc[j] = fmaf(xv.x, wv.x, acc[j]);
                    acc[j] = fmaf(xv.y, wv.y, acc[j]);
                    acc[j] = fmaf(xv.z, wv.z, acc[j]);
                    acc[j] = fmaf(xv.w, wv.w, acc[j]);
                }
            }
            #pragma unroll
            for (int j = 0; j < 8; j++) {
                int n = base + wid * 8 + j;
                if (n < NN) xch[(size_t)n * 128 + ofs + lane] = __float2half(acc[j]);
            }
            if (isGat) {
                float sv[8], dv[8];
                #pragma unroll
                for (int j = 0; j < 8; j++) {
                    sv[j] = wave_sum(acc[j] * asv);
                    dv[j] = wave_sum(acc[j] * adv);
                }
                if (lane < 8) {
                    int n = base + wid * 8 + lane;
                    if (n < NN) {
                        float svx = (lane==0)?sv[0]:(lane==1)?sv[1]:(lane==2)?sv[2]:(lane==3)?sv[3]
                                   :(lane==4)?sv[4]:(lane==5)?sv[5]:(lane==6)?sv[6]:sv[7];
                        float dvx = (lane==0)?dv[0]:(lane==1)?dv[1]:(lane==2)?dv[2]:(lane==3)?dv[3]
                                   :(lane==4)?dv[4]:(lane==5)?dv[5]:(lane==6)?dv[6]:dv[7];
                        float xvv[10];
                        #pragma unroll
                        for (int k = 0; k < 10; k++) xvv[k] = nf[n * 10 + k];
                        float niv = fc2_b[0];
                        #pragma unroll
                        for (int j = 0; j < 10; j++) {
                            float h = fc1_b[j];
                            #pragma unroll
                            for (int k = 0; k < 10; k++) h = fmaf(xvv[k], fc1_w[j * 10 + k], h);
                            h = (h > 0.f) ? h : expm1f(h);
                            niv = fmaf(h, fc2_w[j], niv);
                        }
                        float cx = coord[2 * n], cy = coord[2 * n + 1];
                        float es = svx + dvx;
                        es = (es >= 0.f) ? es : 0.2f * es;
                        snode[n] = make_float4(cx, cy, svx, niv);
                        dnode[n] = make_float4(cx, cy, dvx, 0.f);
                        ps[n] = __expf(es);
                    }
                }
            }
        }
    }
}

// ---------------- K1: per-bin edge pass, ZERO global atomics -------------
__global__ __launch_bounds__(512) void k_edge3(
    const unsigned int* __restrict__ bucket, const unsigned int* __restrict__ gcnt,
    const float4* __restrict__ snode, const float4* __restrict__ dnode,
    uint2* __restrict__ rec, unsigned int* __restrict__ offA,
    unsigned int* __restrict__ cntA, float* __restrict__ dis)
{
    const int bin = blockIdx.x;
    const int d0  = bin * DSTF;
    __shared__ unsigned int cnt[DSTF], off[DSTF], cur[DSTF], ews[DSTF];
    __shared__ float4 dnd[DSTF];
    __shared__ unsigned int segc[NREP];
    __shared__ unsigned int sm[128];
    __shared__ unsigned int wsum[8];
    __shared__ unsigned int sbase;
    for (int t = threadIdx.x; t < DSTF; t += 512) {
        cnt[t] = 0u; cur[t] = 0u; ews[t] = 0u;
        int d = d0 + t;
        dnd[t] = (d < NN) ? dnode[d] : make_float4(0.f, 0.f, 0.f, 0.f);
    }
    if (threadIdx.x < NREP) {
        unsigned int c = gcnt[threadIdx.x * NBIN + bin];
        segc[threadIdx.x] = (c > BCAPR) ? BCAPR : c;
    }
    unsigned int partial = 0u;
    for (int idx = threadIdx.x; idx < NREP * NBIN; idx += 512) {
        int b = idx & (NBIN - 1);
        if (b < bin) {
            unsigned int c = gcnt[(idx >> 9) * NBIN + b];
            partial += (c > BCAPR) ? BCAPR : c;
        }
    }
    #pragma unroll
    for (int o = 32; o > 0; o >>= 1) partial += __shfl_xor(partial, o, 64);
    if ((threadIdx.x & 63) == 0) wsum[threadIdx.x >> 6] = partial;
    __syncthreads();
    if (threadIdx.x == 0) {
        unsigned int a = 0;
        #pragma unroll
        for (int r = 0; r < 8; r++) a += wsum[r];
        sbase = a;
    }
    __syncthreads();
    #pragma unroll
    for (int r = 0; r < NREP; r++) {
        unsigned int c = segc[r];
        const unsigned int* bk = bucket + (size_t)(r * NBIN + bin) * BCAPR;
        for (unsigned int t = threadIdx.x; t < c; t += 512)
            atomicAdd(&cnt[bk[t] >> 16], 1u);
    }
    __syncthreads();
    if (threadIdx.x < 128) sm[threadIdx.x] = (threadIdx.x < DSTF) ? cnt[threadIdx.x] : 0u;
    __syncthreads();
    for (int o = 1; o < 128; o <<= 1) {
        unsigned int t = 0;
        if (threadIdx.x < 128 && threadIdx.x >= o) t = sm[threadIdx.x - o];
        __syncthreads();
        if (threadIdx.x < 128) sm[threadIdx.x] += t;
        __syncthreads();
    }
    if (threadIdx.x < DSTF) off[threadIdx.x] = sbase + sm[threadIdx.x] - cnt[threadIdx.x];
    __syncthreads();
    #pragma unroll
    for (int r = 0; r < NREP; r++) {
        unsigned int c = segc[r];
        const unsigned int* bk = bucket + (size_t)(r * NBIN + bin) * BCAPR;
        for (unsigned int t = threadIdx.x; t < c; t += 512) {
            unsigned int pk = bk[t];
            int dl = (int)(pk >> 16);
            int s  = (int)(pk & 0xFFFFu);
            float4 sv = snode[s];
            float4 dv = dnd[dl];
            float dx = sv.x - dv.x, dy = sv.y - dv.y;
            float gw = __expf((dx * dx + dy * dy) * (-1.0f / 1800.0f));
            float tt = fmaf(gw, 1.0f + sv.w, -1.0f);
            float sg = 1.0f / (1.0f + __expf(-tt));
            float w  = fmaf(1.9f, sg, 0.1f);
            float e  = sv.z + dv.z;
            e = (e >= 0.f) ? e : 0.2f * e;
            float ewv = (w >= 0.2f) ? w : 0.0f;
            float p = (ewv != 0.f) ? __expf(e) : 0.0f;
            unsigned int rk = atomicAdd(&cur[dl], 1u);
            atomicAdd(&ews[dl], (unsigned int)(ewv * 16777216.0f + 0.5f));
            __half2 h = __floats2half2_rn(p, ewv);
            rec[off[dl] + rk] = make_uint2((unsigned int)s, *(unsigned int*)&h);
        }
    }
    __syncthreads();
    for (int t = threadIdx.x; t < DSTF; t += 512) {
        int d = d0 + t;
        if (d < NN) {
            offA[d] = off[t];
            cntA[d] = cnt[t];
            dis[d]  = rsqrtf(1.0f + (float)ews[t] * (1.0f / 16777216.0f));
        }
    }
}

// ---------------- K3: fused gather, 8 groups x 8 lanes x uint4 ----------
// Two structurally different versions (R13 4x16xuint2, R14 8x8xuint4)
// both land at ~66us -> bound by the feature-fetch memory system
// (xch 12.8MB > 4MB XCD L2; FETCH 160MB @ ~2.6TB/s). Kept as-is.
__global__ __launch_bounds__(256) void k_gather3(
    const __half* __restrict__ xch,
    const float* __restrict__ ps, const float* __restrict__ dis,
    const unsigned int* __restrict__ offA, const unsigned int* __restrict__ cntA,
    const uint2* __restrict__ rec,
    const float* __restrict__ gat_b, const float* __restrict__ gcn_b,
    uint2* __restrict__ catLh, uint2* __restrict__ catGh)
{
    const int lane = threadIdx.x & 63;
    const int wid  = threadIdx.x >> 6;
    const int eg   = lane >> 3;          // 0..7 edge group
    const int q    = lane & 7;           // uint4 slot within row half
    const int fi   = q * 8;              // first half-index of this lane
    const float g0 = (eg == 0) ? 1.0f : 0.0f;
    const float4 gb0 = *(const float4*)(gat_b + fi);
    const float4 gb1 = *(const float4*)(gat_b + fi + 4);
    const float4 cb0 = *(const float4*)(gcn_b + fi);
    const float4 cb1 = *(const float4*)(gcn_b + fi + 4);
    for (int n = blockIdx.x * 4 + wid; n < NN; n += gridDim.x * 4) {
        float psv = ps[n] * g0;
        float dd = dis[n];
        int beg = (int)offA[n];
        int end = beg + (int)cntA[n];
        const uint4* rowd = (const uint4*)(xch + (size_t)n * 128);
        uint4 us = rowd[q];
        uint4 ug = rowd[q + 8];
        float2 d0 = __half22float2(*(const __half2*)&us.x);
        float2 d1 = __half22float2(*(const __half2*)&us.y);
        float2 d2 = __half22float2(*(const __half2*)&us.z);
        float2 d3 = __half22float2(*(const __half2*)&us.w);
        float2 e0 = __half22float2(*(const __half2*)&ug.x);
        float2 e1 = __half22float2(*(const __half2*)&ug.y);
        float2 e2 = __half22float2(*(const __half2*)&ug.z);
        float2 e3 = __half22float2(*(const __half2*)&ug.w);
        float aL[8], aC[8];
        aL[0] = psv * d0.x; aL[1] = psv * d0.y; aL[2] = psv * d1.x; aL[3] = psv * d1.y;
        aL[4] = psv * d2.x; aL[5] = psv * d2.y; aL[6] = psv * d3.x; aL[7] = psv * d3.y;
        float sw = dd * g0;
        aC[0] = sw * e0.x; aC[1] = sw * e0.y; aC[2] = sw * e1.x; aC[3] = sw * e1.y;
        aC[4] = sw * e2.x; aC[5] = sw * e2.y; aC[6] = sw * e3.x; aC[7] = sw * e3.y;
        float den = psv;
        int j = beg + eg;
        for (; j + 8 < end; j += 16) {
            uint2 r0 = rec[j];
            uint2 r1 = rec[j + 8];
            int s0 = (int)r0.x;
            int s1 = (int)r1.x;
            float2 pc0 = __half22float2(*(const __half2*)&r0.y);
            float2 pc1 = __half22float2(*(const __half2*)&r1.y);
            float c0 = dis[s0] * pc0.y;
            float c1 = dis[s1] * pc1.y;
            const uint4* row0 = (const uint4*)(xch + (size_t)s0 * 128);
            const uint4* row1 = (const uint4*)(xch + (size_t)s1 * 128);
            uint4 l0 = row0[q];
            uint4 g0v = row0[q + 8];
            uint4 l1 = row1[q];
            uint4 g1v = row1[q + 8];
            float2 t0, t1, t2, t3;
            t0 = __half22float2(*(const __half2*)&l0.x);
            t1 = __half22float2(*(const __half2*)&l0.y);
            t2 = __half22float2(*(const __half2*)&l0.z);
            t3 = __half22float2(*(const __half2*)&l0.w);
            aL[0] = fmaf(pc0.x, t0.x, aL[0]); aL[1] = fmaf(pc0.x, t0.y, aL[1]);
            aL[2] = fmaf(pc0.x, t1.x, aL[2]); aL[3] = fmaf(pc0.x, t1.y, aL[3]);
            aL[4] = fmaf(pc0.x, t2.x, aL[4]); aL[5] = fmaf(pc0.x, t2.y, aL[5]);
            aL[6] = fmaf(pc0.x, t3.x, aL[6]); aL[7] = fmaf(pc0.x, t3.y, aL[7]);
            t0 = __half22float2(*(const __half2*)&g0v.x);
            t1 = __half22float2(*(const __half2*)&g0v.y);
            t2 = __half22float2(*(const __half2*)&g0v.z);
            t3 = __half22float2(*(const __half2*)&g0v.w);
            aC[0] = fmaf(c0, t0.x, aC[0]); aC[1] = fmaf(c0, t0.y, aC[1]);
            aC[2] = fmaf(c0, t1.x, aC[2]); aC[3] = fmaf(c0, t1.y, aC[3]);
            aC[4] = fmaf(c0, t2.x, aC[4]); aC[5] = fmaf(c0, t2.y, aC[5]);
            aC[6] = fmaf(c0, t3.x, aC[6]); aC[7] = fmaf(c0, t3.y, aC[7]);
            t0 = __half22float2(*(const __half2*)&l1.x);
            t1 = __half22float2(*(const __half2*)&l1.y);
            t2 = __half22float2(*(const __half2*)&l1.z);
            t3 = __half22float2(*(const __half2*)&l1.w);
            aL[0] = fmaf(pc1.x, t0.x, aL[0]); aL[1] = fmaf(pc1.x, t0.y, aL[1]);
            aL[2] = fmaf(pc1.x, t1.x, aL[2]); aL[3] = fmaf(pc1.x, t1.y, aL[3]);
            aL[4] = fmaf(pc1.x, t2.x, aL[4]); aL[5] = fmaf(pc1.x, t2.y, aL[5]);
            aL[6] = fmaf(pc1.x, t3.x, aL[6]); aL[7] = fmaf(pc1.x, t3.y, aL[7]);
            t0 = __half22float2(*(const __half2*)&g1v.x);
            t1 = __half22float2(*(const __half2*)&g1v.y);
            t2 = __half22float2(*(const __half2*)&g1v.z);
            t3 = __half22float2(*(const __half2*)&g1v.w);
            aC[0] = fmaf(c1, t0.x, aC[0]); aC[1] = fmaf(c1, t0.y, aC[1]);
            aC[2] = fmaf(c1, t1.x, aC[2]); aC[3] = fmaf(c1, t1.y, aC[3]);
            aC[4] = fmaf(c1, t2.x, aC[4]); aC[5] = fmaf(c1, t2.y, aC[5]);
            aC[6] = fmaf(c1, t3.x, aC[6]); aC[7] = fmaf(c1, t3.y, aC[7]);
            den += pc0.x + pc1.x;
        }
        if (j < end) {
            uint2 r0 = rec[j];
            int s0 = (int)r0.x;
            float2 pc0 = __half22float2(*(const __half2*)&r0.y);
            float c0 = dis[s0] * pc0.y;
            const uint4* row0 = (const uint4*)(xch + (size_t)s0 * 128);
            uint4 l0 = row0[q];
            uint4 g0v = row0[q + 8];
            float2 t0, t1, t2, t3;
            t0 = __half22float2(*(const __half2*)&l0.x);
            t1 = __half22float2(*(const __half2*)&l0.y);
            t2 = __half22float2(*(const __half2*)&l0.z);
            t3 = __half22float2(*(const __half2*)&l0.w);
            aL[0] = fmaf(pc0.x, t0.x, aL[0]); aL[1] = fmaf(pc0.x, t0.y, aL[1]);
            aL[2] = fmaf(pc0.x, t1.x, aL[2]); aL[3] = fmaf(pc0.x, t1.y, aL[3]);
            aL[4] = fmaf(pc0.x, t2.x, aL[4]); aL[5] = fmaf(pc0.x, t2.y, aL[5]);
            aL[6] = fmaf(pc0.x, t3.x, aL[6]); aL[7] = fmaf(pc0.x, t3.y, aL[7]);
            t0 = __half22float2(*(const __half2*)&g0v.x);
            t1 = __half22float2(*(const __half2*)&g0v.y);
            t2 = __half22float2(*(const __half2*)&g0v.z);
            t3 = __half22float2(*(const __half2*)&g0v.w);
            aC[0] = fmaf(c0, t0.x, aC[0]); aC[1] = fmaf(c0, t0.y, aC[1]);
            aC[2] = fmaf(c0, t1.x, aC[2]); aC[3] = fmaf(c0, t1.y, aC[3]);
            aC[4] = fmaf(c0, t2.x, aC[4]); aC[5] = fmaf(c0, t2.y, aC[5]);
            aC[6] = fmaf(c0, t3.x, aC[6]); aC[7] = fmaf(c0, t3.y, aC[7]);
            den += pc0.x;
        }
        #pragma unroll
        for (int m = 8; m <= 32; m <<= 1) {
            #pragma unroll
            for (int k = 0; k < 8; k++) {
                aL[k] += __shfl_xor(aL[k], m, 64);
                aC[k] += __shfl_xor(aC[k], m, 64);
            }
            den += __shfl_xor(den, m, 64);
        }
        if (eg == 0) {
            float rd = 1.0f / den;
            float la[8], ga[8];
            la[0] = fmaf(aL[0], rd, gb0.x); la[1] = fmaf(aL[1], rd, gb0.y);
            la[2] = fmaf(aL[2], rd, gb0.z); la[3] = fmaf(aL[3], rd, gb0.w);
            la[4] = fmaf(aL[4], rd, gb1.x); la[5] = fmaf(aL[5], rd, gb1.y);
            la[6] = fmaf(aL[6], rd, gb1.z); la[7] = fmaf(aL[7], rd, gb1.w);
            ga[0] = fmaxf(fmaf(dd, aC[0], cb0.x), 0.f);
            ga[1] = fmaxf(fmaf(dd, aC[1], cb0.y), 0.f);
            ga[2] = fmaxf(fmaf(dd, aC[2], cb0.z), 0.f);
            ga[3] = fmaxf(fmaf(dd, aC[3], cb0.w), 0.f);
            ga[4] = fmaxf(fmaf(dd, aC[4], cb1.x), 0.f);
            ga[5] = fmaxf(fmaf(dd, aC[5], cb1.y), 0.f);
            ga[6] = fmaxf(fmaf(dd, aC[6], cb1.z), 0.f);
            ga[7] = fmaxf(fmaf(dd, aC[7], cb1.w), 0.f);
            #pragma unroll
            for (int k = 0; k < 8; k++)
                la[k] = (la[k] > 0.f) ? la[k] : expm1f(la[k]);
            __half2 l01 = __floats2half2_rn(la[0], la[1]);
            __half2 l23 = __floats2half2_rn(la[2], la[3]);
            __half2 l45 = __floats2half2_rn(la[4], la[5]);
            __half2 l67 = __floats2half2_rn(la[6], la[7]);
            __half2 g01 = __floats2half2_rn(ga[0], ga[1]);
            __half2 g23 = __floats2half2_rn(ga[2], ga[3]);
            __half2 g45 = __floats2half2_rn(ga[4], ga[5]);
            __half2 g67 = __floats2half2_rn(ga[6], ga[7]);
            catLh[(size_t)n * 16 + q * 2] =
                make_uint2(*(unsigned int*)&l01, *(unsigned int*)&l23);
            catLh[(size_t)n * 16 + q * 2 + 1] =
                make_uint2(*(unsigned int*)&l45, *(unsigned int*)&l67);
            catGh[(size_t)n * 16 + q * 2] =
                make_uint2(*(unsigned int*)&g01, *(unsigned int*)&g23);
            catGh[(size_t)n * 16 + q * 2 + 1] =
                make_uint2(*(unsigned int*)&g45, *(unsigned int*)&g67);
        }
    }
}

// ---------------- K4: fusion head, LDS-staged weights ----------------
__global__ __launch_bounds__(256) void k_fuse(
    const uint2* __restrict__ catLh, const uint2* __restrict__ catGh,
    const float* __restrict__ fus_w1, const float* __restrict__ fus_b1,
    const float* __restrict__ fus_w2, const float* __restrict__ fus_b2,
    float* __restrict__ out)
{
    __shared__ float wS[64 * 132];      // 33.8 KB
    __shared__ uint2 catS[32 * 33];     // 8.4 KB
    const int nb = blockIdx.x * 32;
    for (int f = threadIdx.x; f < 64 * 128; f += 256) {
        int r = f >> 7, c = f & 127;
        wS[r * 132 + c] = fus_w1[f];
    }
    for (int f = threadIdx.x; f < 32 * 32; f += 256) {
        int i = f >> 5, c = f & 31;
        int n = nb + i;
        uint2 v = make_uint2(0u, 0u);
        if (n < NN) v = (c < 16) ? catLh[(size_t)n * 16 + c]
                                 : catGh[(size_t)n * 16 + (c - 16)];
        catS[i * 33 + c] = v;
    }
    __syncthreads();
    const int p = threadIdx.x >> 3;     // local node 0..31
    const int q = threadIdx.x & 7;      // hid slice
    const int n = nb + p;
    float hid[8];
    #pragma unroll
    for (int j = 0; j < 8; j++) {
        int jj = (q + j) & 7;
        hid[j] = fus_b1[q * 8 + jj];
    }
    const uint2* cp = catS + p * 33;
    #pragma unroll 2
    for (int kb = 0; kb < 32; kb++) {   // unified cols: kb*4 covers 0..127
        uint2 u = cp[kb];
        float2 a = __half22float2(*(const __half2*)&u.x);
        float2 b = __half22float2(*(const __half2*)&u.y);
        #pragma unroll
        for (int j = 0; j < 8; j++) {
            int jj = (q + j) & 7;
            float4 wv = *(const float4*)(wS + (size_t)(q * 8 + jj) * 132 + kb * 4);
            hid[j] = fmaf(wv.x, a.x, hid[j]);
            hid[j] = fmaf(wv.y, a.y, hid[j]);
            hid[j] = fmaf(wv.z, b.x, hid[j]);
            hid[j] = fmaf(wv.w, b.y, hid[j]);
        }
    }
    float acc = 0.f;
    #pragma unroll
    for (int j = 0; j < 8; j++) {
        int jj = (q + j) & 7;
        acc = fmaf(fmaxf(hid[j], 0.f), fus_w2[q * 8 + jj], acc);
    }
    acc += __shfl_xor(acc, 1, 64);
    acc += __shfl_xor(acc, 2, 64);
    acc += __shfl_xor(acc, 4, 64);
    if (q == 0 && n < NN) out[n] = acc + fus_b2[0];
}

extern "C" void kernel_launch(void* const* d_in, const int* in_sizes, int n_in,
                              void* d_out, int out_size, void* d_ws, size_t ws_size,
                              hipStream_t stream)
{
    const float* x_local  = (const float*)d_in[0];
    const float* x_global = (const float*)d_in[1];
    const float* nf       = (const float*)d_in[2];
    const float* coord    = (const float*)d_in[3];
    const int*   ei       = (const int*)d_in[4];
    const float* fc1_w    = (const float*)d_in[5];
    const float* fc1_b    = (const float*)d_in[6];
    const float* fc2_w    = (const float*)d_in[7];
    const float* fc2_b    = (const float*)d_in[8];
    const float* gat_w    = (const float*)d_in[9];
    const float* att_src  = (const float*)d_in[10];
    const float* att_dst  = (const float*)d_in[11];
    const float* gat_b    = (const float*)d_in[12];
    const float* gcn_w    = (const float*)d_in[13];
    const float* gcn_b    = (const float*)d_in[14];
    const float* fus_w1   = (const float*)d_in[15];
    const float* fus_b1   = (const float*)d_in[16];
    const float* fus_w2   = (const float*)d_in[17];
    const float* fus_b2   = (const float*)d_in[18];
    float* out = (float*)d_out;

    char* ws = (char*)d_ws;
    uint2*  rec  = (uint2*) (ws);                       // compact CSR 1.6M*8 = 12,800,000
    __half* xch  = (__half*)(ws + 12800000);            // interleaved L|C, 12,800,000
    uint2*  catLh= (uint2*) (ws + 25600000);            //  6,400,000
    uint2*  catGh= (uint2*) (ws + 32000000);            //  6,400,000
    // bucket OVERLAYS cat region: dead before k_gather3 writes cat*
    unsigned int* bucket = (unsigned int*)(ws + 25600000); // 8*512*576*4 = 9,437,184
    float4* snode= (float4*)(ws + 38400000);            //    800,000
    float4* dnode= (float4*)(ws + 39200000);            //    800,000
    unsigned int* offA = (unsigned int*)(ws + 40000000);//    200,000
    unsigned int* cntA = (unsigned int*)(ws + 40200000);//    200,000
    float*  dis  = (float*) (ws + 40400000);            //    200,000
    float*  ps   = (float*) (ws + 40600000);            //    200,000
    unsigned int* gcnt = (unsigned int*)(ws + 40800000);//     16,384 -> end ~40.82 MB
    (void)in_sizes; (void)n_in; (void)out_size; (void)ws_size;

    k_zerog<<<(NREP * NBIN + 255) / 256, 256, 0, stream>>>(gcnt);
    k_front<<<3 * NBF, 256, 0, stream>>>(ei, bucket, gcnt,
                                         x_local, gat_w, att_src, att_dst,
                                         nf, coord, fc1_w, fc1_b, fc2_w, fc2_b,
                                         x_global, gcn_w,
                                         xch, snode, dnode, ps);
    k_edge3<<<NBIN, 512, 0, stream>>>(bucket, gcnt, snode, dnode,
                                      rec, offA, cntA, dis);
    k_gather3<<<3125, 256, 0, stream>>>(xch, ps, dis, offA, cntA, rec,
                                        gat_b, gcn_b, catLh, catGh);
    k_fuse<<<(NN + 31) / 32, 256, 0, stream>>>(catLh, catGh,
                                               fus_w1, fus_b1, fus_w2, fus_b2, out);
}